// Round 6
// baseline (125.810 us; speedup 1.0000x reference)
//
#include <hip/hip_runtime.h>
#include <hip/hip_cooperative_groups.h>
#include <stdint.h>

namespace cg = cooperative_groups;

#define NITEMS 10000
#define EDIM 32
#define NWORDS 5000   // NITEMS/2 packed u16 pairs

// ---- fused cooperative config ----
constexpr int NBF = 250;            // blocks (all co-resident via cooperative launch)
constexpr int TBF = 1024;           // per-block hist updates = 4M/250 = 16000 < 2^16 -> u16 safe
constexpr int WPB = NWORDS / NBF;   // 20 packed words per block
constexpr int IPF = 2 * WPB;        // 40 items per block
constexpr int CHK = 25;             // merge row-chunks
constexpr int RPC2 = NBF / CHK;     // 10 rows per chunk

// fused ws layout (needs 5,096,000 B):
//   [0, 5,000,000)            u32 hist_g[250][5000]
//   [5,000,000, 5,064,000)    double partials[250][32]
//   [5,064,000, 5,096,000)    u64 cand[250*16]
// R5 fallback layout (needs 5,133,696 B) / R2 fallback (~69KB) below.

__device__ __forceinline__ unsigned long long umax64(unsigned long long a, unsigned long long b) {
    return a > b ? a : b;
}
__device__ __forceinline__ unsigned long long wave_max64(unsigned long long v) {
    #pragma unroll
    for (int off = 32; off > 0; off >>= 1)
        v = umax64(v, __shfl_xor(v, off));
    return v;
}

// ================= single fused cooperative kernel =================

__global__ __launch_bounds__(TBF, 4) void fused_all(
    const int* __restrict__ hist, int H,
    uint32_t* __restrict__ hist_g,
    const float* __restrict__ emb,
    double* __restrict__ partials,          // [NBF][32]
    unsigned long long* __restrict__ cand,  // [NBF*K]
    int* __restrict__ out,
    double invH, int K)
{
    __shared__ uint32_t hcnt[NWORDS];       // packed u16 pair bins
    __shared__ uint32_t pLo[CHK][32];
    __shared__ uint32_t pHi[CHK][32];
    __shared__ int cnt[IPF];
    __shared__ double sred[32][32];
    __shared__ float um[EDIM];
    __shared__ unsigned long long wlds[16 * 16];  // per-wave top-K staging (K<=16)

    int t = threadIdx.x;
    int b = blockIdx.x;

    // ---- P1: per-block LDS histogram, spill to hist_g ----
    for (int i = t; i < NWORDS; i += TBF) hcnt[i] = 0;
    __syncthreads();
    {
        int tid = b * TBF + t, nth = gridDim.x * TBF;
        const int4* h4 = (const int4*)hist;
        int H4 = H >> 2;
        for (int i = tid; i < H4; i += nth) {   // ~4 iterations
            int4 v = h4[i];
            atomicAdd(&hcnt[v.x >> 1], 1u << ((v.x & 1) << 4));
            atomicAdd(&hcnt[v.y >> 1], 1u << ((v.y & 1) << 4));
            atomicAdd(&hcnt[v.z >> 1], 1u << ((v.z & 1) << 4));
            atomicAdd(&hcnt[v.w >> 1], 1u << ((v.w & 1) << 4));
        }
        for (int i = (H4 << 2) + tid; i < H; i += nth) {
            int v = hist[i];
            atomicAdd(&hcnt[v >> 1], 1u << ((v & 1) << 4));
        }
    }
    __syncthreads();
    {
        uint32_t* dst = hist_g + (size_t)b * NWORDS;
        for (int i = t; i < NWORDS; i += TBF) dst[i] = hcnt[i];
    }
    cg::this_grid().sync();

    // ---- P2: merge own 20 words over 250 rows, then embsum for own 40 items ----
    {
        int w_idx = t & 31, chunk = t >> 5;
        if (w_idx < WPB && chunk < CHK) {
            uint32_t lo = 0, hi = 0;
            const uint32_t* src = hist_g + (size_t)(chunk * RPC2) * NWORDS + b * WPB + w_idx;
            #pragma unroll
            for (int r = 0; r < RPC2; ++r) {
                uint32_t v = src[(size_t)r * NWORDS];
                lo += v & 0xFFFFu;
                hi += v >> 16;
            }
            pLo[chunk][w_idx] = lo;
            pHi[chunk][w_idx] = hi;
        }
        __syncthreads();
        if (t < WPB) {
            uint32_t lo = 0, hi = 0;
            #pragma unroll
            for (int c = 0; c < CHK; ++c) { lo += pLo[c][t]; hi += pHi[c][t]; }
            cnt[2 * t]     = (int)lo;
            cnt[2 * t + 1] = (int)hi;
        }
        __syncthreads();
        int d = t & 31, g = t >> 5;
        double acc = 0.0;
        for (int i = g; i < IPF; i += 32)   // 1-2 iterations
            acc += (double)cnt[i] * (double)emb[(size_t)(b * IPF + i) * EDIM + d];
        sred[g][d] = acc;
        __syncthreads();
        if (t < 32) {
            double s = sred[0][t];
            #pragma unroll
            for (int g2 = 1; g2 < 32; ++g2) s += sred[g2][t];
            partials[b * 32 + t] = s;
        }
    }
    cg::this_grid().sync();

    // ---- P3: um = reduce(partials)/H; wave 0 scores own 40 items + local top-K ----
    {
        int d = t & 31, g = t >> 5;
        double acc = 0.0;
        for (int r = g; r < NBF; r += 32)   // ~8 iterations, coalesced
            acc += partials[r * 32 + d];
        sred[g][d] = acc;
        __syncthreads();
        if (t < 32) {
            double s = sred[0][t];
            #pragma unroll
            for (int g2 = 1; g2 < 32; ++g2) s += sred[g2][t];
            um[t] = (float)(s * invH);
        }
        __syncthreads();
        if (t < 64) {
            // Pack (score_bits, ~idx): u64 max == (higher score, then lower index).
            // Scores >= 0 (emb in [0,1), counts >= 0) so float bits are monotone.
            unsigned long long my = 0ull;
            if (t < IPF) {
                int item = b * IPF + t;
                const float4* row = (const float4*)(emb + (size_t)item * EDIM);
                float sc = 0.f;
                #pragma unroll
                for (int q = 0; q < EDIM / 4; ++q) {
                    float4 v = row[q];
                    sc += um[4 * q + 0] * v.x + um[4 * q + 1] * v.y
                        + um[4 * q + 2] * v.z + um[4 * q + 3] * v.w;
                }
                my = ((unsigned long long)__float_as_uint(sc) << 32)
                   | (unsigned long long)(0xFFFFFFFFu - (unsigned int)item);
            }
            for (int j = 0; j < K; ++j) {   // single-wave top-K, no barriers
                unsigned long long win = wave_max64(my);
                if (t == 0) cand[b * K + j] = win;
                if (my == win) my = 0ull;   // item ids unique -> one owner
            }
        }
    }
    cg::this_grid().sync();

    // ---- P4: block 0 reduces cand[NBF*K] -> out[K] (two-stage, shfl-heavy) ----
    if (b == 0) {
        int lane = t & 63, w = t >> 6;
        int NC = NBF * K;                   // 2500 for K=10 (<= 3*TBF)
        unsigned long long r0 = 0, r1 = 0, r2 = 0;
        if (t < NC)           r0 = cand[t];
        if (t + TBF < NC)     r1 = cand[t + TBF];
        if (t + 2 * TBF < NC) r2 = cand[t + 2 * TBF];
        for (int j = 0; j < K; ++j) {       // per-wave top-K (no block barriers)
            unsigned long long m = umax64(umax64(r0, r1), r2);
            unsigned long long win = wave_max64(m);
            if (lane == 0) wlds[w * K + j] = win;
            if (r0 == win) r0 = 0;
            if (r1 == win) r1 = 0;
            if (r2 == win) r2 = 0;
        }
        __syncthreads();
        if (w == 0) {
            int NE = 16 * K;                // 160
            unsigned long long s0 = (lane < NE)       ? wlds[lane]       : 0ull;
            unsigned long long s1 = (64 + lane < NE)  ? wlds[64 + lane]  : 0ull;
            unsigned long long s2 = (128 + lane < NE) ? wlds[128 + lane] : 0ull;
            unsigned long long s3 = (192 + lane < NE) ? wlds[192 + lane] : 0ull;
            for (int j = 0; j < K; ++j) {
                unsigned long long m = umax64(umax64(s0, s1), umax64(s2, s3));
                unsigned long long win = wave_max64(m);
                if (lane == 0) out[j] = (int)(0xFFFFFFFFu - (unsigned int)(win & 0xFFFFFFFFull));
                if (s0 == win) s0 = 0;
                if (s1 == win) s1 = 0;
                if (s2 == win) s2 = 0;
                if (s3 == win) s3 = 0;
            }
        }
    }
}

// ================= R5 fallback path (proven, 3 kernels) =================

constexpr int NBH = 256;
constexpr int TBH = 1024;
constexpr int NBE = 40;
constexpr int TBE = 1024;
constexpr int WPB5 = NWORDS / NBE;    // 125
constexpr int IPEB = 2 * WPB5;        // 250
constexpr int CHUNKS = 8;
constexpr int RPC = NBH / CHUNKS;     // 32
constexpr int NBS = 40;
constexpr int TBS = 256;
constexpr int IPB = (NITEMS + NBS - 1) / NBS;

__global__ __launch_bounds__(TBH) void k1_hist(
    const int* __restrict__ hist, int H,
    uint32_t* __restrict__ hist_g,
    unsigned int* __restrict__ counter)
{
    __shared__ uint32_t cnt[NWORDS];
    for (int i = threadIdx.x; i < NWORDS; i += TBH) cnt[i] = 0;
    if (blockIdx.x == 0 && threadIdx.x == 0) *counter = 0;
    __syncthreads();

    int tid = blockIdx.x * TBH + threadIdx.x;
    int nth = gridDim.x * TBH;
    const int4* h4 = (const int4*)hist;
    int H4 = H >> 2;
    for (int i = tid; i < H4; i += nth) {
        int4 v = h4[i];
        atomicAdd(&cnt[v.x >> 1], 1u << ((v.x & 1) << 4));
        atomicAdd(&cnt[v.y >> 1], 1u << ((v.y & 1) << 4));
        atomicAdd(&cnt[v.z >> 1], 1u << ((v.z & 1) << 4));
        atomicAdd(&cnt[v.w >> 1], 1u << ((v.w & 1) << 4));
    }
    for (int i = (H4 << 2) + tid; i < H; i += nth) {
        int v = hist[i];
        atomicAdd(&cnt[v >> 1], 1u << ((v & 1) << 4));
    }
    __syncthreads();

    uint32_t* dst = hist_g + (size_t)blockIdx.x * NWORDS;
    for (int i = threadIdx.x; i < NWORDS; i += TBH) dst[i] = cnt[i];
}

__global__ __launch_bounds__(TBE) void k2_merge_embsum(
    const uint32_t* __restrict__ hist_g,
    const float* __restrict__ emb,
    double* __restrict__ partials)
{
    __shared__ uint32_t partLo[CHUNKS][WPB5 + 3];
    __shared__ uint32_t partHi[CHUNKS][WPB5 + 3];
    __shared__ int cnt[IPEB];
    __shared__ double sred[TBE / 32][32];

    int t = threadIdx.x;
    int w_idx = t & 127;
    int chunk = t >> 7;
    int wbase = blockIdx.x * WPB5;

    if (w_idx < WPB5) {
        uint32_t lo = 0, hi = 0;
        const uint32_t* src = hist_g + (size_t)(chunk * RPC) * NWORDS + wbase + w_idx;
        #pragma unroll 8
        for (int r = 0; r < RPC; ++r) {
            uint32_t v = src[(size_t)r * NWORDS];
            lo += v & 0xFFFFu;
            hi += v >> 16;
        }
        partLo[chunk][w_idx] = lo;
        partHi[chunk][w_idx] = hi;
    }
    __syncthreads();

    if (t < WPB5) {
        uint32_t lo = 0, hi = 0;
        #pragma unroll
        for (int c = 0; c < CHUNKS; ++c) { lo += partLo[c][t]; hi += partHi[c][t]; }
        cnt[2 * t]     = (int)lo;
        cnt[2 * t + 1] = (int)hi;
    }
    __syncthreads();

    int d = t & 31;
    int g = t >> 5;
    int ibase = blockIdx.x * IPEB;
    double acc = 0.0;
    for (int i = g; i < IPEB; i += TBE / 32)
        acc += (double)cnt[i] * (double)emb[(ibase + i) * EDIM + d];
    sred[g][d] = acc;
    __syncthreads();
    if (t < 32) {
        double s = sred[0][t];
        #pragma unroll
        for (int g2 = 1; g2 < TBE / 32; ++g2) s += sred[g2][t];
        partials[blockIdx.x * 32 + t] = s;
    }
}

__global__ __launch_bounds__(1024) void k1_fb_hist_embsum(
    const int* __restrict__ hist, int H,
    const float* __restrict__ emb,
    double* __restrict__ partials)
{
    __shared__ int cnt[NITEMS];
    __shared__ double sred[32][32];

    for (int i = threadIdx.x; i < NITEMS; i += 1024) cnt[i] = 0;
    __syncthreads();

    int tid = blockIdx.x * 1024 + threadIdx.x;
    int nth = gridDim.x * 1024;
    const int4* h4 = (const int4*)hist;
    int H4 = H >> 2;
    for (int i = tid; i < H4; i += nth) {
        int4 v = h4[i];
        atomicAdd(&cnt[v.x], 1);
        atomicAdd(&cnt[v.y], 1);
        atomicAdd(&cnt[v.z], 1);
        atomicAdd(&cnt[v.w], 1);
    }
    for (int i = (H4 << 2) + tid; i < H; i += nth) atomicAdd(&cnt[hist[i]], 1);
    __syncthreads();

    int d = threadIdx.x & 31;
    int g = threadIdx.x >> 5;
    double acc = 0.0;
    for (int i = g; i < NITEMS; i += 32)
        acc += (double)cnt[i] * (double)emb[i * EDIM + d];
    sred[g][d] = acc;
    __syncthreads();
    if (threadIdx.x < 32) {
        double s = 0.0;
        #pragma unroll
        for (int g2 = 0; g2 < 32; ++g2) s += sred[g2][threadIdx.x];
        partials[blockIdx.x * 32 + threadIdx.x] = s;
    }
}

__global__ __launch_bounds__(TBS) void k3_score_topk(
    const double* __restrict__ partials, int nparts,
    const float* __restrict__ emb,
    double invH,
    unsigned long long* __restrict__ cand,
    unsigned int* __restrict__ counter,
    int* __restrict__ out, int K)
{
    __shared__ double sred[TBS / 32][32];
    __shared__ float um[EDIM];
    __shared__ unsigned long long wred[TBS / 64];
    __shared__ unsigned long long winner;
    __shared__ int lastFlag;

    int t = threadIdx.x;
    int lane = t & 63;
    int wv = t >> 6;
    constexpr int NW = TBS / 64;

    {
        int d = t & 31;
        int g = t >> 5;
        double acc = 0.0;
        for (int b = g; b < nparts; b += TBS / 32)
            acc += partials[b * EDIM + d];
        sred[g][d] = acc;
        __syncthreads();
        if (t < 32) {
            double s = sred[0][t];
            #pragma unroll
            for (int g2 = 1; g2 < TBS / 32; ++g2) s += sred[g2][t];
            um[t] = (float)(s * invH);
        }
        __syncthreads();
    }

    int item = blockIdx.x * IPB + t;
    unsigned long long my = 0ull;
    if (t < IPB && item < NITEMS) {
        const float4* row = (const float4*)(emb + (size_t)item * EDIM);
        float sc = 0.f;
        #pragma unroll
        for (int q = 0; q < EDIM / 4; ++q) {
            float4 v = row[q];
            sc += um[q * 4 + 0] * v.x + um[q * 4 + 1] * v.y
                + um[q * 4 + 2] * v.z + um[q * 4 + 3] * v.w;
        }
        unsigned int sb = __float_as_uint(sc);
        my = ((unsigned long long)sb << 32)
           | (unsigned long long)(0xFFFFFFFFu - (unsigned int)item);
    }

    for (int it = 0; it < K; ++it) {
        unsigned long long w = wave_max64(my);
        if (lane == 0) wred[wv] = w;
        __syncthreads();
        if (t == 0) {
            unsigned long long win = wred[0];
            #pragma unroll
            for (int j = 1; j < NW; ++j) win = umax64(win, wred[j]);
            winner = win;
            __hip_atomic_store(&cand[blockIdx.x * K + it], win,
                               __ATOMIC_RELAXED, __HIP_MEMORY_SCOPE_AGENT);
        }
        __syncthreads();
        if (my == winner) my = 0ull;
    }

    if (t == 0) {
        unsigned int prev = __hip_atomic_fetch_add(counter, 1u,
                               __ATOMIC_ACQ_REL, __HIP_MEMORY_SCOPE_AGENT);
        lastFlag = (prev == (unsigned int)(gridDim.x - 1));
    }
    __syncthreads();
    if (!lastFlag) return;

    int NC = gridDim.x * K;
    unsigned long long a = 0ull, b = 0ull;
    if (t < NC)
        a = __hip_atomic_load(&cand[t], __ATOMIC_RELAXED, __HIP_MEMORY_SCOPE_AGENT);
    if (t + TBS < NC)
        b = __hip_atomic_load(&cand[t + TBS], __ATOMIC_RELAXED, __HIP_MEMORY_SCOPE_AGENT);

    for (int it = 0; it < K; ++it) {
        unsigned long long m = umax64(a, b);
        unsigned long long w = wave_max64(m);
        if (lane == 0) wred[wv] = w;
        __syncthreads();
        if (t == 0) {
            unsigned long long win = wred[0];
            #pragma unroll
            for (int j = 1; j < NW; ++j) win = umax64(win, wred[j]);
            winner = win;
            out[it] = (int)(0xFFFFFFFFu - (unsigned int)(win & 0xFFFFFFFFull));
        }
        __syncthreads();
        unsigned long long win = winner;
        if (a == win) a = 0ull;
        if (b == win) b = 0ull;
    }
}

extern "C" void kernel_launch(void* const* d_in, const int* in_sizes, int n_in,
                              void* d_out, int out_size, void* d_ws, size_t ws_size,
                              hipStream_t stream) {
    const int*   hist = (const int*)d_in[0];
    const float* emb  = (const float*)d_in[1];
    int H = in_sizes[0];
    int K = out_size;  // 10
    double invH = 1.0 / (double)H;
    char* ws = (char*)d_ws;

    constexpr size_t FUSED_WS = 5096000;
    constexpr size_t FAST_WS  = 5133696;

    // Query cooperative-launch support fresh each call (no static caching).
    int dev = 0, coop = 0;
    hipGetDevice(&dev);
    hipDeviceGetAttribute(&coop, hipDeviceAttributeCooperativeLaunch, dev);

    bool launched = false;
    if (coop && K <= 16 && ws_size >= FUSED_WS) {
        uint32_t* hist_g         = (uint32_t*)ws;
        double* partials         = (double*)(ws + 5000000);
        unsigned long long* cand = (unsigned long long*)(ws + 5064000);
        int* outp                = (int*)d_out;

        void* args[] = { (void*)&hist, (void*)&H, (void*)&hist_g, (void*)&emb,
                         (void*)&partials, (void*)&cand, (void*)&outp,
                         (void*)&invH, (void*)&K };
        hipError_t e = hipLaunchCooperativeKernel((const void*)fused_all,
                                                  dim3(NBF), dim3(TBF),
                                                  args, 0, stream);
        launched = (e == hipSuccess);
    }

    if (!launched && ws_size >= FAST_WS) {
        // R5 proven 3-kernel path
        uint32_t* hist_g         = (uint32_t*)ws;
        double* partials         = (double*)(ws + 5120000);
        unsigned int* counter    = (unsigned int*)(ws + 5130240);
        unsigned long long* cand = (unsigned long long*)(ws + 5130496);

        hipLaunchKernelGGL(k1_hist, dim3(NBH), dim3(TBH), 0, stream,
                           hist, H, hist_g, counter);
        hipLaunchKernelGGL(k2_merge_embsum, dim3(NBE), dim3(TBE), 0, stream,
                           hist_g, emb, partials);
        hipLaunchKernelGGL(k3_score_topk, dim3(NBS), dim3(TBS), 0, stream,
                           partials, NBE, emb, invH, cand, counter, (int*)d_out, K);
        launched = true;
    }

    if (!launched) {
        // R2 minimal-ws path
        double* partials         = (double*)ws;
        unsigned int* counter    = (unsigned int*)(ws + 65536);
        unsigned long long* cand = (unsigned long long*)(ws + 65792);

        hipMemsetAsync(counter, 0, sizeof(unsigned int), stream);
        hipLaunchKernelGGL(k1_fb_hist_embsum, dim3(256), dim3(1024), 0, stream,
                           hist, H, emb, partials);
        hipLaunchKernelGGL(k3_score_topk, dim3(NBS), dim3(TBS), 0, stream,
                           partials, 256, emb, invH, cand, counter, (int*)d_out, K);
    }
}

// Round 7
// 56.694 us; speedup vs baseline: 2.2191x; 2.2191x over previous
//
#include <hip/hip_runtime.h>
#include <stdint.h>

#define NITEMS 10000
#define EDIM 32
#define NWORDS 5000   // NITEMS/2 packed u16 pairs

// ---- config ----
constexpr int NBH = 256;              // histogram blocks
constexpr int TBH = 1024;             // per-block updates = 4M/256 = 15625 < 2^16 -> u16 safe
constexpr int NBF = 40;               // fused merge+score blocks (cooperative)
constexpr int TBF = 1024;
constexpr int WPB = NWORDS / NBF;     // 125 packed words per block
constexpr int IPF = 2 * WPB;          // 250 items per block
constexpr int CHUNKS = 8;
constexpr int RPC = NBH / CHUNKS;     // 32 rows per chunk
// fallback (R5) kernels reuse these shapes
constexpr int NBS = 40;
constexpr int TBS = 256;
constexpr int IPB = (NITEMS + NBS - 1) / NBS;

// ws layout (needs 5,133,696 B):
//   [0, 5,120,000)            u32 hist_g[256][5000]          (k1 -> k23, cached path)
//   [5,120,000, 5,130,240)    u64 partials[40][32] (doubles) (agent-atomic path)
//   [5,130,240, 5,130,248)    u32 bar[2]: {barrier, fin}     (zeroed by k1 blk0)
//   [5,130,496, 5,133,696)    u64 cand[40*10..16]

__device__ __forceinline__ unsigned long long umax64(unsigned long long a, unsigned long long b) {
    return a > b ? a : b;
}
__device__ __forceinline__ unsigned long long wave_max64(unsigned long long v) {
    #pragma unroll
    for (int off = 32; off > 0; off >>= 1)
        v = umax64(v, __shfl_xor(v, off));
    return v;
}

// ================= k1: histogram + spill =================

__global__ __launch_bounds__(TBH) void k1_hist(
    const int* __restrict__ hist, int H,
    uint32_t* __restrict__ hist_g,
    unsigned int* __restrict__ bar)
{
    __shared__ uint32_t cnt[NWORDS];
    for (int i = threadIdx.x; i < NWORDS; i += TBH) cnt[i] = 0;
    if (blockIdx.x == 0 && threadIdx.x < 2)
        __hip_atomic_store(&bar[threadIdx.x], 0u, __ATOMIC_RELAXED, __HIP_MEMORY_SCOPE_AGENT);
    __syncthreads();

    int tid = blockIdx.x * TBH + threadIdx.x;
    int nth = gridDim.x * TBH;
    const int4* h4 = (const int4*)hist;
    int H4 = H >> 2;
    for (int i = tid; i < H4; i += nth) {
        int4 v = h4[i];
        atomicAdd(&cnt[v.x >> 1], 1u << ((v.x & 1) << 4));
        atomicAdd(&cnt[v.y >> 1], 1u << ((v.y & 1) << 4));
        atomicAdd(&cnt[v.z >> 1], 1u << ((v.z & 1) << 4));
        atomicAdd(&cnt[v.w >> 1], 1u << ((v.w & 1) << 4));
    }
    for (int i = (H4 << 2) + tid; i < H; i += nth) {
        int v = hist[i];
        atomicAdd(&cnt[v >> 1], 1u << ((v & 1) << 4));
    }
    __syncthreads();

    uint32_t* dst = hist_g + (size_t)blockIdx.x * NWORDS;
    for (int i = threadIdx.x; i < TBH * ((NWORDS + TBH - 1) / TBH); i += TBH)
        if (i < NWORDS) dst[i] = cnt[i];
}

// ========== k23: merge + embsum + barrier + score + topk (cooperative) ==========

__global__ __launch_bounds__(TBF) void k23_merge_score(
    const uint32_t* __restrict__ hist_g,
    const float* __restrict__ emb,
    unsigned long long* __restrict__ partials,  // doubles as u64, agent-atomic
    unsigned int* __restrict__ bar,             // [0]=barrier, [1]=fin
    unsigned long long* __restrict__ cand,
    int* __restrict__ out,
    double invH, int K)
{
    __shared__ uint32_t partLo[CHUNKS][WPB + 3];
    __shared__ uint32_t partHi[CHUNKS][WPB + 3];
    __shared__ int cnt[IPF];
    __shared__ double sred[32][32];
    __shared__ float um[EDIM];
    __shared__ unsigned long long wred[TBF / 64];
    __shared__ unsigned long long winner;
    __shared__ unsigned long long wlds[16 * 16];
    __shared__ int lastFlag;

    int t = threadIdx.x;
    int b = blockIdx.x;
    int lane = t & 63, wv = t >> 6;
    constexpr int NW = TBF / 64;  // 16 waves

    // ---- merge own 125 words over 256 rows (cached loads; k1 boundary = coherent) ----
    {
        int w_idx = t & 127, chunk = t >> 7;
        if (w_idx < WPB) {
            uint32_t lo = 0, hi = 0;
            const uint32_t* src = hist_g + (size_t)(chunk * RPC) * NWORDS + b * WPB + w_idx;
            #pragma unroll 8
            for (int r = 0; r < RPC; ++r) {
                uint32_t v = src[(size_t)r * NWORDS];
                lo += v & 0xFFFFu;
                hi += v >> 16;
            }
            partLo[chunk][w_idx] = lo;
            partHi[chunk][w_idx] = hi;
        }
        __syncthreads();
        if (t < WPB) {
            uint32_t lo = 0, hi = 0;
            #pragma unroll
            for (int c = 0; c < CHUNKS; ++c) { lo += partLo[c][t]; hi += partHi[c][t]; }
            cnt[2 * t]     = (int)lo;
            cnt[2 * t + 1] = (int)hi;
        }
        __syncthreads();
    }

    // ---- embsum for own 250 items -> 32-dim partial, publish via agent atomics ----
    int d = t & 31, g = t >> 5;
    {
        double acc = 0.0;
        for (int i = g; i < IPF; i += 32)
            acc += (double)cnt[i] * (double)emb[(size_t)(b * IPF + i) * EDIM + d];
        sred[g][d] = acc;
        __syncthreads();
        if (t < 32) {
            double s = sred[0][t];
            #pragma unroll
            for (int g2 = 1; g2 < 32; ++g2) s += sred[g2][t];
            __hip_atomic_store(&partials[b * 32 + t], __double_as_longlong(s),
                               __ATOMIC_RELAXED, __HIP_MEMORY_SCOPE_AGENT);
        }
        __syncthreads();  // stores complete (vmcnt drained) before arrival
    }

    // ---- hand-rolled grid barrier over 40 co-resident blocks ----
    if (t == 0) {
        __hip_atomic_fetch_add(&bar[0], 1u, __ATOMIC_ACQ_REL, __HIP_MEMORY_SCOPE_AGENT);
        while (__hip_atomic_load(&bar[0], __ATOMIC_ACQUIRE, __HIP_MEMORY_SCOPE_AGENT)
               < (unsigned int)gridDim.x)
            __builtin_amdgcn_s_sleep(1);
    }
    __syncthreads();

    // ---- um = (1/H) * sum over 40 partials (agent-atomic loads) ----
    {
        double acc = 0.0;
        for (int r = g; r < NBF; r += 32) {
            unsigned long long uv = __hip_atomic_load(&partials[r * 32 + d],
                                       __ATOMIC_RELAXED, __HIP_MEMORY_SCOPE_AGENT);
            acc += __longlong_as_double(uv);
        }
        sred[g][d] = acc;
        __syncthreads();
        if (t < 32) {
            double s = sred[0][t];
            #pragma unroll
            for (int g2 = 1; g2 < 32; ++g2) s += sred[g2][t];
            um[t] = (float)(s * invH);
        }
        __syncthreads();
    }

    // ---- score own 250 items. Pack (score_bits, ~idx): u64 max ==
    //      (higher score, then lower index). Scores >= 0 -> bits monotone. ----
    unsigned long long my = 0ull;
    if (t < IPF) {
        int item = b * IPF + t;
        const float4* row = (const float4*)(emb + (size_t)item * EDIM);
        float sc = 0.f;
        #pragma unroll
        for (int q = 0; q < EDIM / 4; ++q) {
            float4 v = row[q];
            sc += um[4 * q + 0] * v.x + um[4 * q + 1] * v.y
                + um[4 * q + 2] * v.z + um[4 * q + 3] * v.w;
        }
        my = ((unsigned long long)__float_as_uint(sc) << 32)
           | (unsigned long long)(0xFFFFFFFFu - (unsigned int)item);
    }
    for (int j = 0; j < K; ++j) {
        unsigned long long w = wave_max64(my);
        if (lane == 0) wred[wv] = w;
        __syncthreads();
        if (t == 0) {
            unsigned long long win = wred[0];
            #pragma unroll
            for (int q = 1; q < NW; ++q) win = umax64(win, wred[q]);
            winner = win;
            __hip_atomic_store(&cand[b * K + j], win,
                               __ATOMIC_RELAXED, __HIP_MEMORY_SCOPE_AGENT);
        }
        __syncthreads();
        if (my == winner) my = 0ull;
    }

    // ---- last block: final reduce cand[NBF*K] -> out[K] ----
    if (t == 0) {
        unsigned int prev = __hip_atomic_fetch_add(&bar[1], 1u,
                               __ATOMIC_ACQ_REL, __HIP_MEMORY_SCOPE_AGENT);
        lastFlag = (prev == (unsigned int)(gridDim.x - 1));
    }
    __syncthreads();
    if (!lastFlag) return;

    int NC = NBF * K;  // <= 640
    unsigned long long r0 = 0ull;
    if (t < NC)
        r0 = __hip_atomic_load(&cand[t], __ATOMIC_RELAXED, __HIP_MEMORY_SCOPE_AGENT);
    for (int j = 0; j < K; ++j) {   // per-wave top-K, no block barriers
        unsigned long long win = wave_max64(r0);
        if (lane == 0) wlds[wv * K + j] = win;
        if (r0 == win) r0 = 0ull;
    }
    __syncthreads();
    if (wv == 0) {
        int NE = NW * K;            // <= 256
        unsigned long long s0 = (lane < NE)       ? wlds[lane]       : 0ull;
        unsigned long long s1 = (64 + lane < NE)  ? wlds[64 + lane]  : 0ull;
        unsigned long long s2 = (128 + lane < NE) ? wlds[128 + lane] : 0ull;
        unsigned long long s3 = (192 + lane < NE) ? wlds[192 + lane] : 0ull;
        for (int j = 0; j < K; ++j) {
            unsigned long long m = umax64(umax64(s0, s1), umax64(s2, s3));
            unsigned long long win = wave_max64(m);
            if (lane == 0) out[j] = (int)(0xFFFFFFFFu - (unsigned int)(win & 0xFFFFFFFFull));
            if (s0 == win) s0 = 0ull;
            if (s1 == win) s1 = 0ull;
            if (s2 == win) s2 = 0ull;
            if (s3 == win) s3 = 0ull;
        }
    }
}

// ================= R5 fallback kernels (proven) =================

__global__ __launch_bounds__(1024) void k2_merge_embsum(
    const uint32_t* __restrict__ hist_g,
    const float* __restrict__ emb,
    double* __restrict__ partials)
{
    __shared__ uint32_t partLo[CHUNKS][WPB + 3];
    __shared__ uint32_t partHi[CHUNKS][WPB + 3];
    __shared__ int cnt[IPF];
    __shared__ double sred[32][32];

    int t = threadIdx.x;
    int w_idx = t & 127;
    int chunk = t >> 7;
    int wbase = blockIdx.x * WPB;

    if (w_idx < WPB) {
        uint32_t lo = 0, hi = 0;
        const uint32_t* src = hist_g + (size_t)(chunk * RPC) * NWORDS + wbase + w_idx;
        #pragma unroll 8
        for (int r = 0; r < RPC; ++r) {
            uint32_t v = src[(size_t)r * NWORDS];
            lo += v & 0xFFFFu;
            hi += v >> 16;
        }
        partLo[chunk][w_idx] = lo;
        partHi[chunk][w_idx] = hi;
    }
    __syncthreads();

    if (t < WPB) {
        uint32_t lo = 0, hi = 0;
        #pragma unroll
        for (int c = 0; c < CHUNKS; ++c) { lo += partLo[c][t]; hi += partHi[c][t]; }
        cnt[2 * t]     = (int)lo;
        cnt[2 * t + 1] = (int)hi;
    }
    __syncthreads();

    int d = t & 31;
    int g = t >> 5;
    int ibase = blockIdx.x * IPF;
    double acc = 0.0;
    for (int i = g; i < IPF; i += 32)
        acc += (double)cnt[i] * (double)emb[(ibase + i) * EDIM + d];
    sred[g][d] = acc;
    __syncthreads();
    if (t < 32) {
        double s = sred[0][t];
        #pragma unroll
        for (int g2 = 1; g2 < 32; ++g2) s += sred[g2][t];
        partials[blockIdx.x * 32 + t] = s;
    }
}

__global__ __launch_bounds__(1024) void k1_fb_hist_embsum(
    const int* __restrict__ hist, int H,
    const float* __restrict__ emb,
    double* __restrict__ partials)
{
    __shared__ int cnt[NITEMS];
    __shared__ double sred[32][32];

    for (int i = threadIdx.x; i < NITEMS; i += 1024) cnt[i] = 0;
    __syncthreads();

    int tid = blockIdx.x * 1024 + threadIdx.x;
    int nth = gridDim.x * 1024;
    const int4* h4 = (const int4*)hist;
    int H4 = H >> 2;
    for (int i = tid; i < H4; i += nth) {
        int4 v = h4[i];
        atomicAdd(&cnt[v.x], 1);
        atomicAdd(&cnt[v.y], 1);
        atomicAdd(&cnt[v.z], 1);
        atomicAdd(&cnt[v.w], 1);
    }
    for (int i = (H4 << 2) + tid; i < H; i += nth) atomicAdd(&cnt[hist[i]], 1);
    __syncthreads();

    int d = threadIdx.x & 31;
    int g = threadIdx.x >> 5;
    double acc = 0.0;
    for (int i = g; i < NITEMS; i += 32)
        acc += (double)cnt[i] * (double)emb[i * EDIM + d];
    sred[g][d] = acc;
    __syncthreads();
    if (threadIdx.x < 32) {
        double s = 0.0;
        #pragma unroll
        for (int g2 = 0; g2 < 32; ++g2) s += sred[g2][threadIdx.x];
        partials[blockIdx.x * 32 + threadIdx.x] = s;
    }
}

__global__ __launch_bounds__(TBS) void k3_score_topk(
    const double* __restrict__ partials, int nparts,
    const float* __restrict__ emb,
    double invH,
    unsigned long long* __restrict__ cand,
    unsigned int* __restrict__ counter,
    int* __restrict__ out, int K)
{
    __shared__ double sred[TBS / 32][32];
    __shared__ float um[EDIM];
    __shared__ unsigned long long wred[TBS / 64];
    __shared__ unsigned long long winner;
    __shared__ int lastFlag;

    int t = threadIdx.x;
    int lane = t & 63;
    int wv = t >> 6;
    constexpr int NW = TBS / 64;

    {
        int d = t & 31;
        int g = t >> 5;
        double acc = 0.0;
        for (int b = g; b < nparts; b += TBS / 32)
            acc += partials[b * EDIM + d];
        sred[g][d] = acc;
        __syncthreads();
        if (t < 32) {
            double s = sred[0][t];
            #pragma unroll
            for (int g2 = 1; g2 < TBS / 32; ++g2) s += sred[g2][t];
            um[t] = (float)(s * invH);
        }
        __syncthreads();
    }

    int item = blockIdx.x * IPB + t;
    unsigned long long my = 0ull;
    if (t < IPB && item < NITEMS) {
        const float4* row = (const float4*)(emb + (size_t)item * EDIM);
        float sc = 0.f;
        #pragma unroll
        for (int q = 0; q < EDIM / 4; ++q) {
            float4 v = row[q];
            sc += um[q * 4 + 0] * v.x + um[q * 4 + 1] * v.y
                + um[q * 4 + 2] * v.z + um[q * 4 + 3] * v.w;
        }
        unsigned int sb = __float_as_uint(sc);
        my = ((unsigned long long)sb << 32)
           | (unsigned long long)(0xFFFFFFFFu - (unsigned int)item);
    }

    for (int it = 0; it < K; ++it) {
        unsigned long long w = wave_max64(my);
        if (lane == 0) wred[wv] = w;
        __syncthreads();
        if (t == 0) {
            unsigned long long win = wred[0];
            #pragma unroll
            for (int j = 1; j < NW; ++j) win = umax64(win, wred[j]);
            winner = win;
            __hip_atomic_store(&cand[blockIdx.x * K + it], win,
                               __ATOMIC_RELAXED, __HIP_MEMORY_SCOPE_AGENT);
        }
        __syncthreads();
        if (my == winner) my = 0ull;
    }

    if (t == 0) {
        unsigned int prev = __hip_atomic_fetch_add(counter, 1u,
                               __ATOMIC_ACQ_REL, __HIP_MEMORY_SCOPE_AGENT);
        lastFlag = (prev == (unsigned int)(gridDim.x - 1));
    }
    __syncthreads();
    if (!lastFlag) return;

    int NC = gridDim.x * K;
    unsigned long long a = 0ull, b = 0ull;
    if (t < NC)
        a = __hip_atomic_load(&cand[t], __ATOMIC_RELAXED, __HIP_MEMORY_SCOPE_AGENT);
    if (t + TBS < NC)
        b = __hip_atomic_load(&cand[t + TBS], __ATOMIC_RELAXED, __HIP_MEMORY_SCOPE_AGENT);

    for (int it = 0; it < K; ++it) {
        unsigned long long m = umax64(a, b);
        unsigned long long w = wave_max64(m);
        if (lane == 0) wred[wv] = w;
        __syncthreads();
        if (t == 0) {
            unsigned long long win = wred[0];
            #pragma unroll
            for (int j = 1; j < NW; ++j) win = umax64(win, wred[j]);
            winner = win;
            out[it] = (int)(0xFFFFFFFFu - (unsigned int)(win & 0xFFFFFFFFull));
        }
        __syncthreads();
        unsigned long long win = winner;
        if (a == win) a = 0ull;
        if (b == win) b = 0ull;
    }
}

extern "C" void kernel_launch(void* const* d_in, const int* in_sizes, int n_in,
                              void* d_out, int out_size, void* d_ws, size_t ws_size,
                              hipStream_t stream) {
    const int*   hist = (const int*)d_in[0];
    const float* emb  = (const float*)d_in[1];
    int H = in_sizes[0];
    int K = out_size;  // 10
    double invH = 1.0 / (double)H;
    char* ws = (char*)d_ws;

    constexpr size_t FAST_WS = 5133696;

    if (ws_size >= FAST_WS) {
        uint32_t* hist_g           = (uint32_t*)ws;
        unsigned long long* partu  = (unsigned long long*)(ws + 5120000);
        unsigned int* bar          = (unsigned int*)(ws + 5130240);
        unsigned long long* cand   = (unsigned long long*)(ws + 5130496);
        int* outp                  = (int*)d_out;

        hipLaunchKernelGGL(k1_hist, dim3(NBH), dim3(TBH), 0, stream,
                           hist, H, hist_g, bar);

        bool fusedOk = false;
        int dev = 0, coop = 0;
        hipGetDevice(&dev);
        hipDeviceGetAttribute(&coop, hipDeviceAttributeCooperativeLaunch, dev);
        if (coop && K <= 16) {
            void* args[] = { (void*)&hist_g, (void*)&emb, (void*)&partu,
                             (void*)&bar, (void*)&cand, (void*)&outp,
                             (void*)&invH, (void*)&K };
            hipError_t e = hipLaunchCooperativeKernel((const void*)k23_merge_score,
                                                      dim3(NBF), dim3(TBF),
                                                      args, 0, stream);
            fusedOk = (e == hipSuccess);
        }

        if (!fusedOk) {
            // proven R5 tail: separate merge+embsum then score+topk
            double* partials = (double*)(ws + 5120000);
            hipLaunchKernelGGL(k2_merge_embsum, dim3(NBF), dim3(1024), 0, stream,
                               hist_g, emb, partials);
            hipLaunchKernelGGL(k3_score_topk, dim3(NBS), dim3(TBS), 0, stream,
                               partials, NBF, emb, invH, cand, &bar[1], outp, K);
        }
    } else {
        // R2 minimal-ws path
        double* partials         = (double*)ws;
        unsigned int* counter    = (unsigned int*)(ws + 65536);
        unsigned long long* cand = (unsigned long long*)(ws + 65792);

        hipMemsetAsync(counter, 0, sizeof(unsigned int), stream);
        hipLaunchKernelGGL(k1_fb_hist_embsum, dim3(256), dim3(1024), 0, stream,
                           hist, H, emb, partials);
        hipLaunchKernelGGL(k3_score_topk, dim3(NBS), dim3(TBS), 0, stream,
                           partials, 256, emb, invH, cand, counter, (int*)d_out, K);
    }
}

// Round 8
// 39.622 us; speedup vs baseline: 3.1752x; 1.4309x over previous
//
#include <hip/hip_runtime.h>
#include <stdint.h>

#define NITEMS 10000
#define EDIM 32
#define NWORDS 5000   // NITEMS/2 packed u16 pairs

// ---- config ----
constexpr int NBH = 256;              // histogram blocks
constexpr int TBH = 1024;             // per-block updates = 4M/256 = 15625 < 2^16 -> u16 safe
constexpr int NBF = 40;               // fused merge+score blocks (regular launch, de-facto co-resident)
constexpr int TBF = 1024;
constexpr int WPB = NWORDS / NBF;     // 125 packed words per block
constexpr int IPF = 2 * WPB;          // 250 items per block
constexpr int CHUNKS = 8;
constexpr int RPC = NBH / CHUNKS;     // 32 rows per chunk
constexpr int NBS = 40;               // fallback scoring blocks
constexpr int TBS = 256;
constexpr int IPB = (NITEMS + NBS - 1) / NBS;

// ws layout (needs 5,133,696 B):
//   [0, 5,120,000)            u32 hist_g[256][5000]          (k1 -> k23, cached; kernel boundary = coherent)
//   [5,120,000, 5,130,240)    u64 partials[40][32] (doubles) (agent-atomic exchange inside k23)
//   [5,130,240, 5,130,248)    u32 bar[2]: {barrier, fin}     (zeroed by k1 blk0; kernel boundary = coherent)
//   [5,130,496, 5,133,696)    u64 cand[40*16]

__device__ __forceinline__ unsigned long long umax64(unsigned long long a, unsigned long long b) {
    return a > b ? a : b;
}
__device__ __forceinline__ unsigned long long wave_max64(unsigned long long v) {
    #pragma unroll
    for (int off = 32; off > 0; off >>= 1)
        v = umax64(v, __shfl_xor(v, off));
    return v;
}

// ================= k1: histogram + spill =================

__global__ __launch_bounds__(TBH) void k1_hist(
    const int* __restrict__ hist, int H,
    uint32_t* __restrict__ hist_g,
    unsigned int* __restrict__ bar)
{
    __shared__ uint32_t cnt[NWORDS];
    for (int i = threadIdx.x; i < NWORDS; i += TBH) cnt[i] = 0;
    if (blockIdx.x == 0 && threadIdx.x < 2)
        __hip_atomic_store(&bar[threadIdx.x], 0u, __ATOMIC_RELAXED, __HIP_MEMORY_SCOPE_AGENT);
    __syncthreads();

    int tid = blockIdx.x * TBH + threadIdx.x;
    int nth = gridDim.x * TBH;
    const int4* h4 = (const int4*)hist;
    int H4 = H >> 2;
    for (int i = tid; i < H4; i += nth) {       // ~4 iterations
        int4 v = h4[i];
        atomicAdd(&cnt[v.x >> 1], 1u << ((v.x & 1) << 4));
        atomicAdd(&cnt[v.y >> 1], 1u << ((v.y & 1) << 4));
        atomicAdd(&cnt[v.z >> 1], 1u << ((v.z & 1) << 4));
        atomicAdd(&cnt[v.w >> 1], 1u << ((v.w & 1) << 4));
    }
    for (int i = (H4 << 2) + tid; i < H; i += nth) {
        int v = hist[i];
        atomicAdd(&cnt[v >> 1], 1u << ((v & 1) << 4));
    }
    __syncthreads();

    uint32_t* dst = hist_g + (size_t)blockIdx.x * NWORDS;
    for (int i = threadIdx.x; i < NWORDS; i += TBH) dst[i] = cnt[i];
}

// ========== k23: merge + embsum + spin-barrier + score + topk (REGULAR launch) ==========
// 40 blocks x 1024 on a 256-CU chip: the whole grid is dispatched before any block
// can retire (none retire before the barrier), so all blocks are co-resident.
// Cross-block data goes through agent-scope atomics only (partials/bar/cand) —
// no cache maintenance needed. Logic identical to R7's cooperative version (proven
// correct); only the launch API changed (cooperative dispatch cost ~27us, measured R7).

__global__ __launch_bounds__(TBF) void k23_merge_score(
    const uint32_t* __restrict__ hist_g,
    const float* __restrict__ emb,
    unsigned long long* __restrict__ partials,  // doubles as u64, agent-atomic
    unsigned int* __restrict__ bar,             // [0]=barrier, [1]=fin
    unsigned long long* __restrict__ cand,
    int* __restrict__ out,
    double invH, int K)
{
    __shared__ uint32_t partLo[CHUNKS][WPB + 3];
    __shared__ uint32_t partHi[CHUNKS][WPB + 3];
    __shared__ int cnt[IPF];
    __shared__ double sred[32][32];
    __shared__ float um[EDIM];
    __shared__ unsigned long long wred[TBF / 64];
    __shared__ unsigned long long winner;
    __shared__ unsigned long long wlds[16 * 16];
    __shared__ int lastFlag;

    int t = threadIdx.x;
    int b = blockIdx.x;
    int lane = t & 63, wv = t >> 6;
    constexpr int NW = TBF / 64;  // 16 waves

    // ---- merge own 125 words over 256 rows (plain cached loads; k1 boundary = coherent) ----
    {
        int w_idx = t & 127, chunk = t >> 7;
        if (w_idx < WPB) {
            uint32_t lo = 0, hi = 0;
            const uint32_t* src = hist_g + (size_t)(chunk * RPC) * NWORDS + b * WPB + w_idx;
            #pragma unroll 8
            for (int r = 0; r < RPC; ++r) {
                uint32_t v = src[(size_t)r * NWORDS];
                lo += v & 0xFFFFu;
                hi += v >> 16;
            }
            partLo[chunk][w_idx] = lo;
            partHi[chunk][w_idx] = hi;
        }
        __syncthreads();
        if (t < WPB) {
            uint32_t lo = 0, hi = 0;
            #pragma unroll
            for (int c = 0; c < CHUNKS; ++c) { lo += partLo[c][t]; hi += partHi[c][t]; }
            cnt[2 * t]     = (int)lo;
            cnt[2 * t + 1] = (int)hi;
        }
        __syncthreads();
    }

    // ---- embsum for own 250 items -> 32-dim partial, publish via agent atomics ----
    int d = t & 31, g = t >> 5;
    {
        double acc = 0.0;
        for (int i = g; i < IPF; i += 32)
            acc += (double)cnt[i] * (double)emb[(size_t)(b * IPF + i) * EDIM + d];
        sred[g][d] = acc;
        __syncthreads();
        if (t < 32) {
            double s = sred[0][t];
            #pragma unroll
            for (int g2 = 1; g2 < 32; ++g2) s += sred[g2][t];
            __hip_atomic_store(&partials[b * 32 + t], __double_as_longlong(s),
                               __ATOMIC_RELAXED, __HIP_MEMORY_SCOPE_AGENT);
        }
        __syncthreads();  // vmcnt drained -> stores complete before arrival
    }

    // ---- hand-rolled grid barrier over 40 co-resident blocks ----
    if (t == 0) {
        __hip_atomic_fetch_add(&bar[0], 1u, __ATOMIC_ACQ_REL, __HIP_MEMORY_SCOPE_AGENT);
        while (__hip_atomic_load(&bar[0], __ATOMIC_ACQUIRE, __HIP_MEMORY_SCOPE_AGENT)
               < (unsigned int)gridDim.x)
            __builtin_amdgcn_s_sleep(1);
    }
    __syncthreads();

    // ---- um = (1/H) * sum over 40 partials (agent-atomic loads) ----
    {
        double acc = 0.0;
        for (int r = g; r < NBF; r += 32) {
            unsigned long long uv = __hip_atomic_load(&partials[r * 32 + d],
                                       __ATOMIC_RELAXED, __HIP_MEMORY_SCOPE_AGENT);
            acc += __longlong_as_double(uv);
        }
        sred[g][d] = acc;
        __syncthreads();
        if (t < 32) {
            double s = sred[0][t];
            #pragma unroll
            for (int g2 = 1; g2 < 32; ++g2) s += sred[g2][t];
            um[t] = (float)(s * invH);
        }
        __syncthreads();
    }

    // ---- score own 250 items. Pack (score_bits, ~idx): u64 max ==
    //      (higher score, then lower index). Scores >= 0 -> bits monotone. ----
    unsigned long long my = 0ull;
    if (t < IPF) {
        int item = b * IPF + t;
        const float4* row = (const float4*)(emb + (size_t)item * EDIM);
        float sc = 0.f;
        #pragma unroll
        for (int q = 0; q < EDIM / 4; ++q) {
            float4 v = row[q];
            sc += um[4 * q + 0] * v.x + um[4 * q + 1] * v.y
                + um[4 * q + 2] * v.z + um[4 * q + 3] * v.w;
        }
        my = ((unsigned long long)__float_as_uint(sc) << 32)
           | (unsigned long long)(0xFFFFFFFFu - (unsigned int)item);
    }
    for (int j = 0; j < K; ++j) {
        unsigned long long w = wave_max64(my);
        if (lane == 0) wred[wv] = w;
        __syncthreads();
        if (t == 0) {
            unsigned long long win = wred[0];
            #pragma unroll
            for (int q = 1; q < NW; ++q) win = umax64(win, wred[q]);
            winner = win;
            __hip_atomic_store(&cand[b * K + j], win,
                               __ATOMIC_RELAXED, __HIP_MEMORY_SCOPE_AGENT);
        }
        __syncthreads();
        if (my == winner) my = 0ull;
    }

    // ---- last block: final reduce cand[NBF*K] -> out[K] ----
    if (t == 0) {
        unsigned int prev = __hip_atomic_fetch_add(&bar[1], 1u,
                               __ATOMIC_ACQ_REL, __HIP_MEMORY_SCOPE_AGENT);
        lastFlag = (prev == (unsigned int)(gridDim.x - 1));
    }
    __syncthreads();
    if (!lastFlag) return;

    int NC = NBF * K;  // <= 640
    unsigned long long r0 = 0ull;
    if (t < NC)
        r0 = __hip_atomic_load(&cand[t], __ATOMIC_RELAXED, __HIP_MEMORY_SCOPE_AGENT);
    for (int j = 0; j < K; ++j) {   // per-wave top-K, no block barriers
        unsigned long long win = wave_max64(r0);
        if (lane == 0) wlds[wv * K + j] = win;
        if (r0 == win) r0 = 0ull;
    }
    __syncthreads();
    if (wv == 0) {
        int NE = NW * K;            // <= 256
        unsigned long long s0 = (lane < NE)       ? wlds[lane]       : 0ull;
        unsigned long long s1 = (64 + lane < NE)  ? wlds[64 + lane]  : 0ull;
        unsigned long long s2 = (128 + lane < NE) ? wlds[128 + lane] : 0ull;
        unsigned long long s3 = (192 + lane < NE) ? wlds[192 + lane] : 0ull;
        for (int j = 0; j < K; ++j) {
            unsigned long long m = umax64(umax64(s0, s1), umax64(s2, s3));
            unsigned long long win = wave_max64(m);
            if (lane == 0) out[j] = (int)(0xFFFFFFFFu - (unsigned int)(win & 0xFFFFFFFFull));
            if (s0 == win) s0 = 0ull;
            if (s1 == win) s1 = 0ull;
            if (s2 == win) s2 = 0ull;
            if (s3 == win) s3 = 0ull;
        }
    }
}

// ================= R2 fallback kernels (minimal ws) =================

__global__ __launch_bounds__(1024) void k1_fb_hist_embsum(
    const int* __restrict__ hist, int H,
    const float* __restrict__ emb,
    double* __restrict__ partials)
{
    __shared__ int cnt[NITEMS];
    __shared__ double sred[32][32];

    for (int i = threadIdx.x; i < NITEMS; i += 1024) cnt[i] = 0;
    __syncthreads();

    int tid = blockIdx.x * 1024 + threadIdx.x;
    int nth = gridDim.x * 1024;
    const int4* h4 = (const int4*)hist;
    int H4 = H >> 2;
    for (int i = tid; i < H4; i += nth) {
        int4 v = h4[i];
        atomicAdd(&cnt[v.x], 1);
        atomicAdd(&cnt[v.y], 1);
        atomicAdd(&cnt[v.z], 1);
        atomicAdd(&cnt[v.w], 1);
    }
    for (int i = (H4 << 2) + tid; i < H; i += nth) atomicAdd(&cnt[hist[i]], 1);
    __syncthreads();

    int d = threadIdx.x & 31;
    int g = threadIdx.x >> 5;
    double acc = 0.0;
    for (int i = g; i < NITEMS; i += 32)
        acc += (double)cnt[i] * (double)emb[i * EDIM + d];
    sred[g][d] = acc;
    __syncthreads();
    if (threadIdx.x < 32) {
        double s = 0.0;
        #pragma unroll
        for (int g2 = 0; g2 < 32; ++g2) s += sred[g2][threadIdx.x];
        partials[blockIdx.x * 32 + threadIdx.x] = s;
    }
}

__global__ __launch_bounds__(TBS) void k3_score_topk(
    const double* __restrict__ partials, int nparts,
    const float* __restrict__ emb,
    double invH,
    unsigned long long* __restrict__ cand,
    unsigned int* __restrict__ counter,
    int* __restrict__ out, int K)
{
    __shared__ double sred[TBS / 32][32];
    __shared__ float um[EDIM];
    __shared__ unsigned long long wred[TBS / 64];
    __shared__ unsigned long long winner;
    __shared__ int lastFlag;

    int t = threadIdx.x;
    int lane = t & 63;
    int wv = t >> 6;
    constexpr int NW = TBS / 64;

    {
        int d = t & 31;
        int g = t >> 5;
        double acc = 0.0;
        for (int b = g; b < nparts; b += TBS / 32)
            acc += partials[b * EDIM + d];
        sred[g][d] = acc;
        __syncthreads();
        if (t < 32) {
            double s = sred[0][t];
            #pragma unroll
            for (int g2 = 1; g2 < TBS / 32; ++g2) s += sred[g2][t];
            um[t] = (float)(s * invH);
        }
        __syncthreads();
    }

    int item = blockIdx.x * IPB + t;
    unsigned long long my = 0ull;
    if (t < IPB && item < NITEMS) {
        const float4* row = (const float4*)(emb + (size_t)item * EDIM);
        float sc = 0.f;
        #pragma unroll
        for (int q = 0; q < EDIM / 4; ++q) {
            float4 v = row[q];
            sc += um[q * 4 + 0] * v.x + um[q * 4 + 1] * v.y
                + um[q * 4 + 2] * v.z + um[q * 4 + 3] * v.w;
        }
        unsigned int sb = __float_as_uint(sc);
        my = ((unsigned long long)sb << 32)
           | (unsigned long long)(0xFFFFFFFFu - (unsigned int)item);
    }

    for (int it = 0; it < K; ++it) {
        unsigned long long w = wave_max64(my);
        if (lane == 0) wred[wv] = w;
        __syncthreads();
        if (t == 0) {
            unsigned long long win = wred[0];
            #pragma unroll
            for (int j = 1; j < NW; ++j) win = umax64(win, wred[j]);
            winner = win;
            __hip_atomic_store(&cand[blockIdx.x * K + it], win,
                               __ATOMIC_RELAXED, __HIP_MEMORY_SCOPE_AGENT);
        }
        __syncthreads();
        if (my == winner) my = 0ull;
    }

    if (t == 0) {
        unsigned int prev = __hip_atomic_fetch_add(counter, 1u,
                               __ATOMIC_ACQ_REL, __HIP_MEMORY_SCOPE_AGENT);
        lastFlag = (prev == (unsigned int)(gridDim.x - 1));
    }
    __syncthreads();
    if (!lastFlag) return;

    int NC = gridDim.x * K;
    unsigned long long a = 0ull, b = 0ull;
    if (t < NC)
        a = __hip_atomic_load(&cand[t], __ATOMIC_RELAXED, __HIP_MEMORY_SCOPE_AGENT);
    if (t + TBS < NC)
        b = __hip_atomic_load(&cand[t + TBS], __ATOMIC_RELAXED, __HIP_MEMORY_SCOPE_AGENT);

    for (int it = 0; it < K; ++it) {
        unsigned long long m = umax64(a, b);
        unsigned long long w = wave_max64(m);
        if (lane == 0) wred[wv] = w;
        __syncthreads();
        if (t == 0) {
            unsigned long long win = wred[0];
            #pragma unroll
            for (int j = 1; j < NW; ++j) win = umax64(win, wred[j]);
            winner = win;
            out[it] = (int)(0xFFFFFFFFu - (unsigned int)(win & 0xFFFFFFFFull));
        }
        __syncthreads();
        unsigned long long win = winner;
        if (a == win) a = 0ull;
        if (b == win) b = 0ull;
    }
}

extern "C" void kernel_launch(void* const* d_in, const int* in_sizes, int n_in,
                              void* d_out, int out_size, void* d_ws, size_t ws_size,
                              hipStream_t stream) {
    const int*   hist = (const int*)d_in[0];
    const float* emb  = (const float*)d_in[1];
    int H = in_sizes[0];
    int K = out_size;  // 10
    double invH = 1.0 / (double)H;
    char* ws = (char*)d_ws;

    constexpr size_t FAST_WS = 5133696;

    if (ws_size >= FAST_WS && K <= 16) {
        uint32_t* hist_g           = (uint32_t*)ws;
        unsigned long long* partu  = (unsigned long long*)(ws + 5120000);
        unsigned int* bar          = (unsigned int*)(ws + 5130240);
        unsigned long long* cand   = (unsigned long long*)(ws + 5130496);
        int* outp                  = (int*)d_out;

        hipLaunchKernelGGL(k1_hist, dim3(NBH), dim3(TBH), 0, stream,
                           hist, H, hist_g, bar);
        hipLaunchKernelGGL(k23_merge_score, dim3(NBF), dim3(TBF), 0, stream,
                           hist_g, emb, partu, bar, cand, outp, invH, K);
    } else {
        // R2 minimal-ws path
        double* partials         = (double*)ws;
        unsigned int* counter    = (unsigned int*)(ws + 65536);
        unsigned long long* cand = (unsigned long long*)(ws + 65792);

        hipMemsetAsync(counter, 0, sizeof(unsigned int), stream);
        hipLaunchKernelGGL(k1_fb_hist_embsum, dim3(256), dim3(1024), 0, stream,
                           hist, H, emb, partials);
        hipLaunchKernelGGL(k3_score_topk, dim3(NBS), dim3(TBS), 0, stream,
                           partials, 256, emb, invH, cand, counter, (int*)d_out, K);
    }
}

// Round 9
// 38.732 us; speedup vs baseline: 3.2482x; 1.0230x over previous
//
#include <hip/hip_runtime.h>
#include <stdint.h>

#define NITEMS 10000
#define EDIM 32
#define NWORDS 5000   // NITEMS/2 packed u16 pairs

// ---- config ----
constexpr int NBH = 256;              // histogram blocks
constexpr int TBH = 1024;             // per-block updates = 4M/256 = 15625 < 2^16 -> u16 safe
constexpr int NBF = 40;               // fused merge+score blocks (regular launch, co-resident)
constexpr int TBF = 1024;
constexpr int WPB = NWORDS / NBF;     // 125 packed words per block
constexpr int IPF = 2 * WPB;          // 250 items per block
constexpr int CHUNKS = 8;
constexpr int RPC = NBH / CHUNKS;     // 32 rows per chunk
constexpr int NBS = 40;               // fallback scoring blocks
constexpr int TBS = 256;
constexpr int IPB = (NITEMS + NBS - 1) / NBS;

// ws layout (needs 5,133,696 B):
//   [0, 5,120,000)            u32 hist_g[256][5000]          (k1 -> k23, cached; kernel boundary = coherent)
//   [5,120,000, 5,130,240)    u64 partials[40][32] (doubles) (agent-atomic exchange inside k23)
//   [5,130,240, 5,130,248)    u32 bar[2]: {barrier, fin}     (zeroed by k1 blk0)
//   [5,130,496, 5,133,696)    u64 cand[40*16]
//
// MEMORY-ORDER NOTE (R8 lesson): agent-scope ACQUIRE/ACQ_REL on gfx950 emit
// buffer_inv (L2 invalidate, per-XCD L2s non-coherent). A spin loop with an
// ACQUIRE load invalidates L2 every iteration -> ~10us regression (R8) and
// explains cg::grid.sync()'s ~30us (R6). All cross-block state here lives
// ONLY in agent-scope atomics (memory-side, L2-bypassing), and __syncthreads
// drains vmcnt before each arrival, so RELAXED everywhere is sufficient and
// emits zero cache-maintenance instructions.

__device__ __forceinline__ unsigned long long umax64(unsigned long long a, unsigned long long b) {
    return a > b ? a : b;
}
__device__ __forceinline__ unsigned long long wave_max64(unsigned long long v) {
    #pragma unroll
    for (int off = 32; off > 0; off >>= 1)
        v = umax64(v, __shfl_xor(v, off));
    return v;
}

// ================= k1: histogram + spill =================

__global__ __launch_bounds__(TBH) void k1_hist(
    const int* __restrict__ hist, int H,
    uint32_t* __restrict__ hist_g,
    unsigned int* __restrict__ bar)
{
    __shared__ uint32_t cnt[NWORDS];
    for (int i = threadIdx.x; i < NWORDS; i += TBH) cnt[i] = 0;
    if (blockIdx.x == 0 && threadIdx.x < 2)
        __hip_atomic_store(&bar[threadIdx.x], 0u, __ATOMIC_RELAXED, __HIP_MEMORY_SCOPE_AGENT);
    __syncthreads();

    int tid = blockIdx.x * TBH + threadIdx.x;
    int nth = gridDim.x * TBH;
    const int4* h4 = (const int4*)hist;
    int H4 = H >> 2;
    for (int i = tid; i < H4; i += nth) {       // ~4 iterations
        int4 v = h4[i];
        atomicAdd(&cnt[v.x >> 1], 1u << ((v.x & 1) << 4));
        atomicAdd(&cnt[v.y >> 1], 1u << ((v.y & 1) << 4));
        atomicAdd(&cnt[v.z >> 1], 1u << ((v.z & 1) << 4));
        atomicAdd(&cnt[v.w >> 1], 1u << ((v.w & 1) << 4));
    }
    for (int i = (H4 << 2) + tid; i < H; i += nth) {
        int v = hist[i];
        atomicAdd(&cnt[v >> 1], 1u << ((v & 1) << 4));
    }
    __syncthreads();

    uint32_t* dst = hist_g + (size_t)blockIdx.x * NWORDS;
    for (int i = threadIdx.x; i < NWORDS; i += TBH) dst[i] = cnt[i];
}

// ========== k23: merge + embsum + relaxed spin-barrier + score + topk ==========

__global__ __launch_bounds__(TBF) void k23_merge_score(
    const uint32_t* __restrict__ hist_g,
    const float* __restrict__ emb,
    unsigned long long* __restrict__ partials,  // doubles as u64, agent-atomic
    unsigned int* __restrict__ bar,             // [0]=barrier, [1]=fin
    unsigned long long* __restrict__ cand,
    int* __restrict__ out,
    double invH, int K)
{
    __shared__ uint32_t partLo[CHUNKS][WPB + 3];
    __shared__ uint32_t partHi[CHUNKS][WPB + 3];
    __shared__ int cnt[IPF];
    __shared__ double sred[32][32];
    __shared__ float um[EDIM];
    __shared__ unsigned long long wred[TBF / 64];
    __shared__ unsigned long long winner;
    __shared__ unsigned long long wlds[16 * 16];
    __shared__ int lastFlag;

    int t = threadIdx.x;
    int b = blockIdx.x;
    int lane = t & 63, wv = t >> 6;
    constexpr int NW = TBF / 64;  // 16 waves

    // ---- merge own 125 words over 256 rows (plain cached loads) ----
    {
        int w_idx = t & 127, chunk = t >> 7;
        if (w_idx < WPB) {
            uint32_t lo = 0, hi = 0;
            const uint32_t* src = hist_g + (size_t)(chunk * RPC) * NWORDS + b * WPB + w_idx;
            #pragma unroll 8
            for (int r = 0; r < RPC; ++r) {
                uint32_t v = src[(size_t)r * NWORDS];
                lo += v & 0xFFFFu;
                hi += v >> 16;
            }
            partLo[chunk][w_idx] = lo;
            partHi[chunk][w_idx] = hi;
        }
        __syncthreads();
        if (t < WPB) {
            uint32_t lo = 0, hi = 0;
            #pragma unroll
            for (int c = 0; c < CHUNKS; ++c) { lo += partLo[c][t]; hi += partHi[c][t]; }
            cnt[2 * t]     = (int)lo;
            cnt[2 * t + 1] = (int)hi;
        }
        __syncthreads();
    }

    // ---- embsum for own 250 items -> 32-dim partial, publish via agent atomics ----
    int d = t & 31, g = t >> 5;
    {
        double acc = 0.0;
        for (int i = g; i < IPF; i += 32)
            acc += (double)cnt[i] * (double)emb[(size_t)(b * IPF + i) * EDIM + d];
        sred[g][d] = acc;
        __syncthreads();
        if (t < 32) {
            double s = sred[0][t];
            #pragma unroll
            for (int g2 = 1; g2 < 32; ++g2) s += sred[g2][t];
            __hip_atomic_store(&partials[b * 32 + t], __double_as_longlong(s),
                               __ATOMIC_RELAXED, __HIP_MEMORY_SCOPE_AGENT);
        }
        __syncthreads();  // s_waitcnt vmcnt(0) before s_barrier -> stores complete
    }

    // ---- relaxed spin barrier over 40 co-resident blocks (no cache maintenance) ----
    if (t == 0) {
        __hip_atomic_fetch_add(&bar[0], 1u, __ATOMIC_RELAXED, __HIP_MEMORY_SCOPE_AGENT);
        while (__hip_atomic_load(&bar[0], __ATOMIC_RELAXED, __HIP_MEMORY_SCOPE_AGENT)
               < (unsigned int)gridDim.x)
            __builtin_amdgcn_s_sleep(1);
    }
    __syncthreads();

    // ---- um = (1/H) * sum over 40 partials (relaxed agent-atomic loads) ----
    {
        double acc = 0.0;
        for (int r = g; r < NBF; r += 32) {
            unsigned long long uv = __hip_atomic_load(&partials[r * 32 + d],
                                       __ATOMIC_RELAXED, __HIP_MEMORY_SCOPE_AGENT);
            acc += __longlong_as_double(uv);
        }
        sred[g][d] = acc;
        __syncthreads();
        if (t < 32) {
            double s = sred[0][t];
            #pragma unroll
            for (int g2 = 1; g2 < 32; ++g2) s += sred[g2][t];
            um[t] = (float)(s * invH);
        }
        __syncthreads();
    }

    // ---- score own 250 items. Pack (score_bits, ~idx): u64 max ==
    //      (higher score, then lower index). Scores >= 0 -> bits monotone. ----
    unsigned long long my = 0ull;
    if (t < IPF) {
        int item = b * IPF + t;
        const float4* row = (const float4*)(emb + (size_t)item * EDIM);
        float sc = 0.f;
        #pragma unroll
        for (int q = 0; q < EDIM / 4; ++q) {
            float4 v = row[q];
            sc += um[4 * q + 0] * v.x + um[4 * q + 1] * v.y
                + um[4 * q + 2] * v.z + um[4 * q + 3] * v.w;
        }
        my = ((unsigned long long)__float_as_uint(sc) << 32)
           | (unsigned long long)(0xFFFFFFFFu - (unsigned int)item);
    }
    for (int j = 0; j < K; ++j) {
        unsigned long long w = wave_max64(my);
        if (lane == 0) wred[wv] = w;
        __syncthreads();
        if (t == 0) {
            unsigned long long win = wred[0];
            #pragma unroll
            for (int q = 1; q < NW; ++q) win = umax64(win, wred[q]);
            winner = win;
            __hip_atomic_store(&cand[b * K + j], win,
                               __ATOMIC_RELAXED, __HIP_MEMORY_SCOPE_AGENT);
        }
        __syncthreads();
        if (my == winner) my = 0ull;
    }

    // ---- last block: final reduce cand[NBF*K] -> out[K] ----
    if (t == 0) {
        unsigned int prev = __hip_atomic_fetch_add(&bar[1], 1u,
                               __ATOMIC_RELAXED, __HIP_MEMORY_SCOPE_AGENT);
        lastFlag = (prev == (unsigned int)(gridDim.x - 1));
    }
    __syncthreads();
    if (!lastFlag) return;

    int NC = NBF * K;  // <= 640
    unsigned long long r0 = 0ull;
    if (t < NC)
        r0 = __hip_atomic_load(&cand[t], __ATOMIC_RELAXED, __HIP_MEMORY_SCOPE_AGENT);
    for (int j = 0; j < K; ++j) {   // per-wave top-K, no block barriers
        unsigned long long win = wave_max64(r0);
        if (lane == 0) wlds[wv * K + j] = win;
        if (r0 == win) r0 = 0ull;
    }
    __syncthreads();
    if (wv == 0) {
        int NE = NW * K;            // <= 256
        unsigned long long s0 = (lane < NE)       ? wlds[lane]       : 0ull;
        unsigned long long s1 = (64 + lane < NE)  ? wlds[64 + lane]  : 0ull;
        unsigned long long s2 = (128 + lane < NE) ? wlds[128 + lane] : 0ull;
        unsigned long long s3 = (192 + lane < NE) ? wlds[192 + lane] : 0ull;
        for (int j = 0; j < K; ++j) {
            unsigned long long m = umax64(umax64(s0, s1), umax64(s2, s3));
            unsigned long long win = wave_max64(m);
            if (lane == 0) out[j] = (int)(0xFFFFFFFFu - (unsigned int)(win & 0xFFFFFFFFull));
            if (s0 == win) s0 = 0ull;
            if (s1 == win) s1 = 0ull;
            if (s2 == win) s2 = 0ull;
            if (s3 == win) s3 = 0ull;
        }
    }
}

// ================= R2 fallback kernels (minimal ws) =================

__global__ __launch_bounds__(1024) void k1_fb_hist_embsum(
    const int* __restrict__ hist, int H,
    const float* __restrict__ emb,
    double* __restrict__ partials)
{
    __shared__ int cnt[NITEMS];
    __shared__ double sred[32][32];

    for (int i = threadIdx.x; i < NITEMS; i += 1024) cnt[i] = 0;
    __syncthreads();

    int tid = blockIdx.x * 1024 + threadIdx.x;
    int nth = gridDim.x * 1024;
    const int4* h4 = (const int4*)hist;
    int H4 = H >> 2;
    for (int i = tid; i < H4; i += nth) {
        int4 v = h4[i];
        atomicAdd(&cnt[v.x], 1);
        atomicAdd(&cnt[v.y], 1);
        atomicAdd(&cnt[v.z], 1);
        atomicAdd(&cnt[v.w], 1);
    }
    for (int i = (H4 << 2) + tid; i < H; i += nth) atomicAdd(&cnt[hist[i]], 1);
    __syncthreads();

    int d = threadIdx.x & 31;
    int g = threadIdx.x >> 5;
    double acc = 0.0;
    for (int i = g; i < NITEMS; i += 32)
        acc += (double)cnt[i] * (double)emb[i * EDIM + d];
    sred[g][d] = acc;
    __syncthreads();
    if (threadIdx.x < 32) {
        double s = 0.0;
        #pragma unroll
        for (int g2 = 0; g2 < 32; ++g2) s += sred[g2][threadIdx.x];
        partials[blockIdx.x * 32 + threadIdx.x] = s;
    }
}

__global__ __launch_bounds__(TBS) void k3_score_topk(
    const double* __restrict__ partials, int nparts,
    const float* __restrict__ emb,
    double invH,
    unsigned long long* __restrict__ cand,
    unsigned int* __restrict__ counter,
    int* __restrict__ out, int K)
{
    __shared__ double sred[TBS / 32][32];
    __shared__ float um[EDIM];
    __shared__ unsigned long long wred[TBS / 64];
    __shared__ unsigned long long winner;
    __shared__ int lastFlag;

    int t = threadIdx.x;
    int lane = t & 63;
    int wv = t >> 6;
    constexpr int NW = TBS / 64;

    {
        int d = t & 31;
        int g = t >> 5;
        double acc = 0.0;
        for (int b = g; b < nparts; b += TBS / 32)
            acc += partials[b * EDIM + d];
        sred[g][d] = acc;
        __syncthreads();
        if (t < 32) {
            double s = sred[0][t];
            #pragma unroll
            for (int g2 = 1; g2 < TBS / 32; ++g2) s += sred[g2][t];
            um[t] = (float)(s * invH);
        }
        __syncthreads();
    }

    int item = blockIdx.x * IPB + t;
    unsigned long long my = 0ull;
    if (t < IPB && item < NITEMS) {
        const float4* row = (const float4*)(emb + (size_t)item * EDIM);
        float sc = 0.f;
        #pragma unroll
        for (int q = 0; q < EDIM / 4; ++q) {
            float4 v = row[q];
            sc += um[q * 4 + 0] * v.x + um[q * 4 + 1] * v.y
                + um[q * 4 + 2] * v.z + um[q * 4 + 3] * v.w;
        }
        unsigned int sb = __float_as_uint(sc);
        my = ((unsigned long long)sb << 32)
           | (unsigned long long)(0xFFFFFFFFu - (unsigned int)item);
    }

    for (int it = 0; it < K; ++it) {
        unsigned long long w = wave_max64(my);
        if (lane == 0) wred[wv] = w;
        __syncthreads();
        if (t == 0) {
            unsigned long long win = wred[0];
            #pragma unroll
            for (int j = 1; j < NW; ++j) win = umax64(win, wred[j]);
            winner = win;
            __hip_atomic_store(&cand[blockIdx.x * K + it], win,
                               __ATOMIC_RELAXED, __HIP_MEMORY_SCOPE_AGENT);
        }
        __syncthreads();
        if (my == winner) my = 0ull;
    }

    if (t == 0) {
        unsigned int prev = __hip_atomic_fetch_add(counter, 1u,
                               __ATOMIC_RELAXED, __HIP_MEMORY_SCOPE_AGENT);
        lastFlag = (prev == (unsigned int)(gridDim.x - 1));
    }
    __syncthreads();
    if (!lastFlag) return;

    int NC = gridDim.x * K;
    unsigned long long a = 0ull, b = 0ull;
    if (t < NC)
        a = __hip_atomic_load(&cand[t], __ATOMIC_RELAXED, __HIP_MEMORY_SCOPE_AGENT);
    if (t + TBS < NC)
        b = __hip_atomic_load(&cand[t + TBS], __ATOMIC_RELAXED, __HIP_MEMORY_SCOPE_AGENT);

    for (int it = 0; it < K; ++it) {
        unsigned long long m = umax64(a, b);
        unsigned long long w = wave_max64(m);
        if (lane == 0) wred[wv] = w;
        __syncthreads();
        if (t == 0) {
            unsigned long long win = wred[0];
            #pragma unroll
            for (int j = 1; j < NW; ++j) win = umax64(win, wred[j]);
            winner = win;
            out[it] = (int)(0xFFFFFFFFu - (unsigned int)(win & 0xFFFFFFFFull));
        }
        __syncthreads();
        unsigned long long win = winner;
        if (a == win) a = 0ull;
        if (b == win) b = 0ull;
    }
}

extern "C" void kernel_launch(void* const* d_in, const int* in_sizes, int n_in,
                              void* d_out, int out_size, void* d_ws, size_t ws_size,
                              hipStream_t stream) {
    const int*   hist = (const int*)d_in[0];
    const float* emb  = (const float*)d_in[1];
    int H = in_sizes[0];
    int K = out_size;  // 10
    double invH = 1.0 / (double)H;
    char* ws = (char*)d_ws;

    constexpr size_t FAST_WS = 5133696;

    if (ws_size >= FAST_WS && K <= 16) {
        uint32_t* hist_g           = (uint32_t*)ws;
        unsigned long long* partu  = (unsigned long long*)(ws + 5120000);
        unsigned int* bar          = (unsigned int*)(ws + 5130240);
        unsigned long long* cand   = (unsigned long long*)(ws + 5130496);
        int* outp                  = (int*)d_out;

        hipLaunchKernelGGL(k1_hist, dim3(NBH), dim3(TBH), 0, stream,
                           hist, H, hist_g, bar);
        hipLaunchKernelGGL(k23_merge_score, dim3(NBF), dim3(TBF), 0, stream,
                           hist_g, emb, partu, bar, cand, outp, invH, K);
    } else {
        // R2 minimal-ws path
        double* partials         = (double*)ws;
        unsigned int* counter    = (unsigned int*)(ws + 65536);
        unsigned long long* cand = (unsigned long long*)(ws + 65792);

        hipMemsetAsync(counter, 0, sizeof(unsigned int), stream);
        hipLaunchKernelGGL(k1_fb_hist_embsum, dim3(256), dim3(1024), 0, stream,
                           hist, H, emb, partials);
        hipLaunchKernelGGL(k3_score_topk, dim3(NBS), dim3(TBS), 0, stream,
                           partials, 256, emb, invH, cand, counter, (int*)d_out, K);
    }
}

// Round 10
// 31.786 us; speedup vs baseline: 3.9580x; 1.2185x over previous
//
#include <hip/hip_runtime.h>
#include <stdint.h>

#define NITEMS 10000
#define EDIM 32
#define NWORDS 5000   // NITEMS/2 packed u16 pairs

// ---- config (R5-proven shapes) ----
constexpr int NBH = 256;              // histogram blocks
constexpr int TBH = 1024;             // per-block updates = 4M/256 = 15625 < 2^16 -> u16 safe
constexpr int NBE = 40;               // merge+embsum blocks
constexpr int TBE = 1024;
constexpr int WPB = NWORDS / NBE;     // 125 packed words per block
constexpr int IPEB = 2 * WPB;         // 250 items per block
constexpr int CHUNKS = 8;
constexpr int RPC = NBH / CHUNKS;     // 32 rows per chunk
constexpr int NBS = 40;               // scoring blocks
constexpr int TBS = 256;
constexpr int IPB = (NITEMS + NBS - 1) / NBS;  // 250

// ws layout (needs 5,133,696 B):
//   [0, 5,120,000)            u32 hist_g[256][5000]
//   [5,120,000, 5,130,240)    double partials[40][32] (plain; kernel-boundary coherent)
//   [5,130,240, 5,130,248)    u32 bar[2] (bar[1] = fin counter; zeroed by k1 blk0)
//   [5,130,496, 5,133,696)    u64 cand[40*16]

__device__ __forceinline__ unsigned long long umax64(unsigned long long a, unsigned long long b) {
    return a > b ? a : b;
}
__device__ __forceinline__ unsigned long long wave_max64(unsigned long long v) {
    #pragma unroll
    for (int off = 32; off > 0; off >>= 1)
        v = umax64(v, __shfl_xor(v, off));
    return v;
}

#define HATOM(v) atomicAdd(&cnt[(v) >> 1], 1u << (((v) & 1) << 4))

// ================= k1: histogram + spill (4-deep load ILP) =================
// R2 counters showed VGPR_Count=12 -> one int4 load in flight, ~4 serialized HBM
// latencies/thread. Each thread owns exactly ceil(H4/nth)<=4 int4s: issue all
// four loads back-to-back, then do the 16 LDS atomics.

__global__ __launch_bounds__(TBH) void k1_hist(
    const int* __restrict__ hist, int H,
    uint32_t* __restrict__ hist_g,
    unsigned int* __restrict__ bar)
{
    __shared__ uint32_t cnt[NWORDS];
    for (int i = threadIdx.x; i < NWORDS; i += TBH) cnt[i] = 0;
    if (blockIdx.x == 0 && threadIdx.x < 2)
        __hip_atomic_store(&bar[threadIdx.x], 0u, __ATOMIC_RELAXED, __HIP_MEMORY_SCOPE_AGENT);
    __syncthreads();

    int tid = blockIdx.x * TBH + threadIdx.x;
    int nth = gridDim.x * TBH;
    const int4* h4 = (const int4*)hist;
    int H4 = H >> 2;

    for (int base = tid; base < H4; base += 4 * nth) {
        int i1 = base + nth, i2 = base + 2 * nth, i3 = base + 3 * nth;
        bool v1 = i1 < H4, v2 = i2 < H4, v3 = i3 < H4;
        int4 a = h4[base];
        int4 b, c, d;
        if (v1) b = h4[i1];          // loads issue under exec mask, all in flight
        if (v2) c = h4[i2];
        if (v3) d = h4[i3];
        HATOM(a.x); HATOM(a.y); HATOM(a.z); HATOM(a.w);
        if (v1) { HATOM(b.x); HATOM(b.y); HATOM(b.z); HATOM(b.w); }
        if (v2) { HATOM(c.x); HATOM(c.y); HATOM(c.z); HATOM(c.w); }
        if (v3) { HATOM(d.x); HATOM(d.y); HATOM(d.z); HATOM(d.w); }
    }
    for (int i = (H4 << 2) + tid; i < H; i += nth) {
        int v = hist[i];
        HATOM(v);
    }
    __syncthreads();

    uint32_t* dst = hist_g + (size_t)blockIdx.x * NWORDS;
    for (int i = threadIdx.x; i < NWORDS; i += TBH) dst[i] = cnt[i];
}

// ================= k2: merge + embsum (R5-exact, proven) =================

__global__ __launch_bounds__(TBE) void k2_merge_embsum(
    const uint32_t* __restrict__ hist_g,
    const float* __restrict__ emb,
    double* __restrict__ partials)   // [NBE][32]
{
    __shared__ uint32_t partLo[CHUNKS][WPB + 3];
    __shared__ uint32_t partHi[CHUNKS][WPB + 3];
    __shared__ int cnt[IPEB];
    __shared__ double sred[TBE / 32][32];

    int t = threadIdx.x;
    int w_idx = t & 127;
    int chunk = t >> 7;
    int wbase = blockIdx.x * WPB;

    if (w_idx < WPB) {
        uint32_t lo = 0, hi = 0;
        const uint32_t* src = hist_g + (size_t)(chunk * RPC) * NWORDS + wbase + w_idx;
        #pragma unroll 8
        for (int r = 0; r < RPC; ++r) {
            uint32_t v = src[(size_t)r * NWORDS];
            lo += v & 0xFFFFu;
            hi += v >> 16;
        }
        partLo[chunk][w_idx] = lo;
        partHi[chunk][w_idx] = hi;
    }
    __syncthreads();

    if (t < WPB) {
        uint32_t lo = 0, hi = 0;
        #pragma unroll
        for (int c = 0; c < CHUNKS; ++c) { lo += partLo[c][t]; hi += partHi[c][t]; }
        cnt[2 * t]     = (int)lo;
        cnt[2 * t + 1] = (int)hi;
    }
    __syncthreads();

    int d = t & 31;
    int g = t >> 5;
    int ibase = blockIdx.x * IPEB;
    double acc = 0.0;
    for (int i = g; i < IPEB; i += TBE / 32)
        acc += (double)cnt[i] * (double)emb[(ibase + i) * EDIM + d];
    sred[g][d] = acc;
    __syncthreads();
    if (t < 32) {
        double s = sred[0][t];
        #pragma unroll
        for (int g2 = 1; g2 < TBE / 32; ++g2) s += sred[g2][t];
        partials[blockIdx.x * 32 + t] = s;
    }
}

// ================= fallback k1 (R2, minimal ws) =================

__global__ __launch_bounds__(1024) void k1_fb_hist_embsum(
    const int* __restrict__ hist, int H,
    const float* __restrict__ emb,
    double* __restrict__ partials)
{
    __shared__ int cnt[NITEMS];
    __shared__ double sred[32][32];

    for (int i = threadIdx.x; i < NITEMS; i += 1024) cnt[i] = 0;
    __syncthreads();

    int tid = blockIdx.x * 1024 + threadIdx.x;
    int nth = gridDim.x * 1024;
    const int4* h4 = (const int4*)hist;
    int H4 = H >> 2;
    for (int i = tid; i < H4; i += nth) {
        int4 v = h4[i];
        atomicAdd(&cnt[v.x], 1);
        atomicAdd(&cnt[v.y], 1);
        atomicAdd(&cnt[v.z], 1);
        atomicAdd(&cnt[v.w], 1);
    }
    for (int i = (H4 << 2) + tid; i < H; i += nth) atomicAdd(&cnt[hist[i]], 1);
    __syncthreads();

    int d = threadIdx.x & 31;
    int g = threadIdx.x >> 5;
    double acc = 0.0;
    for (int i = g; i < NITEMS; i += 32)
        acc += (double)cnt[i] * (double)emb[i * EDIM + d];
    sred[g][d] = acc;
    __syncthreads();
    if (threadIdx.x < 32) {
        double s = 0.0;
        #pragma unroll
        for (int g2 = 0; g2 < 32; ++g2) s += sred[g2][threadIdx.x];
        partials[blockIdx.x * 32 + threadIdx.x] = s;
    }
}

// ============== k3: score + topk (wave-local tournament, fewer barriers) ==============
// Per-wave top-K (no barriers) -> one __syncthreads -> wave-0 merge. Union of
// per-wave top-Ks contains the global top-K (tournament property). All packed
// candidates are distinct (unique item idx bits) so eliminate-by-equality is safe.

__global__ __launch_bounds__(TBS) void k3_score_topk(
    const double* __restrict__ partials, int nparts,
    const float* __restrict__ emb,
    double invH,
    unsigned long long* __restrict__ cand,
    unsigned int* __restrict__ counter,
    int* __restrict__ out, int K)
{
    __shared__ double sred[TBS / 32][32];
    __shared__ float um[EDIM];
    __shared__ unsigned long long wlds[(TBS / 64) * 16];  // NW*K, K<=16
    __shared__ int lastFlag;

    int t = threadIdx.x;
    int lane = t & 63;
    int wv = t >> 6;
    constexpr int NW = TBS / 64;  // 4 waves

    // um = (1/H) * sum of partials (group-parallel)
    {
        int d = t & 31;
        int g = t >> 5;
        double acc = 0.0;
        for (int b = g; b < nparts; b += TBS / 32)
            acc += partials[b * EDIM + d];
        sred[g][d] = acc;
        __syncthreads();
        if (t < 32) {
            double s = sred[0][t];
            #pragma unroll
            for (int g2 = 1; g2 < TBS / 32; ++g2) s += sred[g2][t];
            um[t] = (float)(s * invH);
        }
        __syncthreads();
    }

    // Score own items. Pack (score_bits, ~idx): u64 max == (higher score, lower idx).
    // Scores >= 0 (emb in [0,1), counts >= 0) so float bits are monotone.
    int item = blockIdx.x * IPB + t;
    unsigned long long my = 0ull;
    if (t < IPB && item < NITEMS) {
        const float4* row = (const float4*)(emb + (size_t)item * EDIM);
        float sc = 0.f;
        #pragma unroll
        for (int q = 0; q < EDIM / 4; ++q) {
            float4 v = row[q];
            sc += um[q * 4 + 0] * v.x + um[q * 4 + 1] * v.y
                + um[q * 4 + 2] * v.z + um[q * 4 + 3] * v.w;
        }
        unsigned int sb = __float_as_uint(sc);
        my = ((unsigned long long)sb << 32)
           | (unsigned long long)(0xFFFFFFFFu - (unsigned int)item);
    }

    // per-wave top-K, barrier-free
    for (int j = 0; j < K; ++j) {
        unsigned long long win = wave_max64(my);
        if (lane == 0) wlds[wv * K + j] = win;
        if (my == win) my = 0ull;
    }
    __syncthreads();
    // wave 0 merges NW*K (<=64) candidates -> block top-K
    if (wv == 0) {
        int NE = NW * K;
        unsigned long long s = (lane < NE) ? wlds[lane] : 0ull;
        for (int j = 0; j < K; ++j) {
            unsigned long long win = wave_max64(s);
            if (lane == 0)
                __hip_atomic_store(&cand[blockIdx.x * K + j], win,
                                   __ATOMIC_RELAXED, __HIP_MEMORY_SCOPE_AGENT);
            if (s == win) s = 0ull;
        }
    }
    __syncthreads();  // vmcnt drained -> cand stores complete before fin bump

    if (t == 0) {
        unsigned int prev = __hip_atomic_fetch_add(counter, 1u,
                               __ATOMIC_RELAXED, __HIP_MEMORY_SCOPE_AGENT);
        lastFlag = (prev == (unsigned int)(gridDim.x - 1));
    }
    __syncthreads();
    if (!lastFlag) return;

    // last block: reduce cand[nblocks*K] -> out[K], wave-local again
    int NC = gridDim.x * K;  // 400
    unsigned long long a = 0ull, b = 0ull;
    if (t < NC)
        a = __hip_atomic_load(&cand[t], __ATOMIC_RELAXED, __HIP_MEMORY_SCOPE_AGENT);
    if (t + TBS < NC)
        b = __hip_atomic_load(&cand[t + TBS], __ATOMIC_RELAXED, __HIP_MEMORY_SCOPE_AGENT);

    for (int j = 0; j < K; ++j) {
        unsigned long long m = umax64(a, b);
        unsigned long long win = wave_max64(m);
        if (lane == 0) wlds[wv * K + j] = win;
        if (a == win) a = 0ull;
        if (b == win) b = 0ull;
    }
    __syncthreads();
    if (wv == 0) {
        int NE = NW * K;
        unsigned long long s = (lane < NE) ? wlds[lane] : 0ull;
        for (int j = 0; j < K; ++j) {
            unsigned long long win = wave_max64(s);
            if (lane == 0) out[j] = (int)(0xFFFFFFFFu - (unsigned int)(win & 0xFFFFFFFFull));
            if (s == win) s = 0ull;
        }
    }
}

extern "C" void kernel_launch(void* const* d_in, const int* in_sizes, int n_in,
                              void* d_out, int out_size, void* d_ws, size_t ws_size,
                              hipStream_t stream) {
    const int*   hist = (const int*)d_in[0];
    const float* emb  = (const float*)d_in[1];
    int H = in_sizes[0];
    int K = out_size;  // 10
    double invH = 1.0 / (double)H;
    char* ws = (char*)d_ws;

    constexpr size_t FAST_WS = 5133696;

    if (ws_size >= FAST_WS && K <= 16) {
        uint32_t* hist_g         = (uint32_t*)ws;
        double* partials         = (double*)(ws + 5120000);
        unsigned int* bar        = (unsigned int*)(ws + 5130240);
        unsigned long long* cand = (unsigned long long*)(ws + 5130496);

        hipLaunchKernelGGL(k1_hist, dim3(NBH), dim3(TBH), 0, stream,
                           hist, H, hist_g, bar);
        hipLaunchKernelGGL(k2_merge_embsum, dim3(NBE), dim3(TBE), 0, stream,
                           hist_g, emb, partials);
        hipLaunchKernelGGL(k3_score_topk, dim3(NBS), dim3(TBS), 0, stream,
                           partials, NBE, emb, invH, cand, &bar[1], (int*)d_out, K);
    } else {
        // R2 minimal-ws path
        double* partials         = (double*)ws;
        unsigned int* counter    = (unsigned int*)(ws + 65536);
        unsigned long long* cand = (unsigned long long*)(ws + 65792);

        hipMemsetAsync(counter, 0, sizeof(unsigned int), stream);
        hipLaunchKernelGGL(k1_fb_hist_embsum, dim3(256), dim3(1024), 0, stream,
                           hist, H, emb, partials);
        hipLaunchKernelGGL(k3_score_topk, dim3(NBS), dim3(TBS), 0, stream,
                           partials, 256, emb, invH, cand, counter, (int*)d_out, K);
    }
}